// Round 6
// baseline (222.023 us; speedup 1.0000x reference)
//
#include <hip/hip_runtime.h>
#include <stdint.h>

// CapsuleLayer dynamic routing, MI355X. fp32 in/out.
// B=256, N=10, I=1152, D=16, K(Din)=8, ROUTINGS=3.
// R6: break intra-block serialization.
//  K1: 4608 short blocks (it x n-half x b-pair), W prefetch pipeline,
//      part0 via shfl + direct atomicAdd (no LDS epilogue).
//  Sweeps: part vectors are atomic-accumulated [b][160]; all u-loads issued
//      before the prologue barrier -> one exposed latency per block.

#define BN 256
#define NN 10
#define II 1152
#define DD 16
#define KK 8
#define NCH 9          // sweep chunks of 128 i
#define CHI 128

typedef unsigned short ushort_t;
typedef unsigned int uint_t;

__device__ __forceinline__ float bflo(uint_t u) {
    union { uint_t i; float f; } v; v.i = u << 16; return v.f;
}
__device__ __forceinline__ float bfhi(uint_t u) {
    union { uint_t i; float f; } v; v.i = u & 0xffff0000u; return v.f;
}
__device__ __forceinline__ uint_t f2bf(float f) {  // RTNE bf16
    union { float f; uint_t i; } v; v.f = f;
    uint_t x = v.i;
    return (x + 0x7fffu + ((x >> 16) & 1u)) >> 16;
}

// ---------------- K1 + sweep0 partials --------------------------------------
// block = (i-tile(64) x n-half(5) x b-pair). 256 thr = 4 waves.
// lane = il*4+dq: thread owns (i = it*64 + wv*16 + il, d-quad dq), 2 b's, 5 n.
// part0[b][n*16+d] += 0.1 * sum_i u  (fp32 atomics, pre-pack values).
__global__ __launch_bounds__(256) void caps_uhat_s0(const float* __restrict__ xg,
                                                    const float* __restrict__ wg,
                                                    ushort_t* __restrict__ u,
                                                    float* __restrict__ part0,
                                                    int b0, int c2)
{
    const int tid = threadIdx.x;
    const int lane = tid & 63, wv = tid >> 6;
    const int dq = lane & 3, il = lane >> 2;
    const int bp = blockIdx.x % c2;
    const int tn = blockIdx.x / c2;       // 0..35, (it,nh)-major for L2 sharing
    const int it = tn >> 1, nh = tn & 1;
    const int bl = bp * 2;
    const int i = it * 64 + wv * 16 + il;
    const int n0 = nh * 5;

    float xv[2][8];
#pragma unroll
    for (int bb = 0; bb < 2; ++bb) {
        const float4* xp = (const float4*)(xg + ((size_t)(b0 + bl + bb) * II + i) * KK);
        float4 x0 = xp[0], x1 = xp[1];
        xv[bb][0] = x0.x; xv[bb][1] = x0.y; xv[bb][2] = x0.z; xv[bb][3] = x0.w;
        xv[bb][4] = x1.x; xv[bb][5] = x1.y; xv[bb][6] = x1.z; xv[bb][7] = x1.w;
    }

    // W pipeline: thread reads W[n][i][dq*4..dq*4+3][*] = 128 contiguous B.
    float4 wcur[8];
    {
        const float4* wp = (const float4*)(wg + (size_t)(n0 * II + i) * (DD * KK)) + dq * 8;
#pragma unroll
        for (int j = 0; j < 8; ++j) wcur[j] = wp[j];
    }

#pragma unroll
    for (int nn = 0; nn < 5; ++nn) {
        const int n = n0 + nn;
        float4 wnxt[8];
        if (nn < 4) {
            const float4* wp = (const float4*)(wg + (size_t)((n + 1) * II + i) * (DD * KK)) + dq * 8;
#pragma unroll
            for (int j = 0; j < 8; ++j) wnxt[j] = wp[j];
        }

        float s[2][4];
#pragma unroll
        for (int dj = 0; dj < 4; ++dj) {
            float4 wa = wcur[2 * dj], wb = wcur[2 * dj + 1];
#pragma unroll
            for (int bb = 0; bb < 2; ++bb) {
                s[bb][dj] = wa.x * xv[bb][0] + wa.y * xv[bb][1]
                          + wa.z * xv[bb][2] + wa.w * xv[bb][3]
                          + wb.x * xv[bb][4] + wb.y * xv[bb][5]
                          + wb.z * xv[bb][6] + wb.w * xv[bb][7];
            }
        }
        // store u (bf16): wave-contiguous 512 B per (b,n)
#pragma unroll
        for (int bb = 0; bb < 2; ++bb) {
            uint2 q;
            q.x = f2bf(s[bb][0]) | (f2bf(s[bb][1]) << 16);
            q.y = f2bf(s[bb][2]) | (f2bf(s[bb][3]) << 16);
            *(uint2*)(u + (((size_t)(bl + bb) * NN + n) * II + i) * DD + dq * 4) = q;
        }
        // reduce over the 16 il lanes, then fire-and-forget atomics
#pragma unroll
        for (int m = 4; m <= 32; m <<= 1)
#pragma unroll
            for (int bb = 0; bb < 2; ++bb)
#pragma unroll
                for (int dj = 0; dj < 4; ++dj)
                    s[bb][dj] += __shfl_xor(s[bb][dj], m, 64);
        if (il == 0) {
#pragma unroll
            for (int bb = 0; bb < 2; ++bb)
#pragma unroll
                for (int dj = 0; dj < 4; ++dj)
                    atomicAdd(part0 + (size_t)(b0 + bl + bb) * 160 + n * 16 + dq * 4 + dj,
                              0.1f * s[bb][dj]);
        }
#pragma unroll
        for (int j = 0; j < 8; ++j) wcur[j] = wnxt[j];
    }
}

// ---------------- sweep r=1,2 ----------------------------------------------
// o = squash(p0[b]); if p1: o += squash(p1[b]).  (p* are full pre-squash sums)
// c = softmax_n(<o,u>), s-partial = sum c*u over 128 i; atomicAdd into pout[b].
__global__ __launch_bounds__(256) void caps_sweep(const ushort_t* __restrict__ u,
                                                  const float* __restrict__ p0,
                                                  const float* __restrict__ p1,
                                                  float* __restrict__ pout, int b0)
{
    __shared__ float red[4 * 160];
    __shared__ float o_s[160];
    const int tid = threadIdx.x, g = tid >> 2, ld = tid & 3;
    const int cb = blockIdx.x / NCH, ch = blockIdx.x % NCH;
    const int b = b0 + cb;
    const ushort_t* ub = u + (size_t)cb * (NN * II * DD);

    // issue ALL u loads first: they drain in the prologue barrier's vmcnt wait.
    const int i0 = ch * CHI + g;
    uint2 r0[NN], r1[NN];
#pragma unroll
    for (int n = 0; n < NN; ++n) {
        r0[n] = *(const uint2*)(ub + ((size_t)(n * II + i0)) * DD + ld * 4);
        r1[n] = *(const uint2*)(ub + ((size_t)(n * II + i0 + 64)) * DD + ld * 4);
    }

    if (tid < 160) {
        float v = p0[(size_t)b * 160 + tid];
        float sq = v * v;
#pragma unroll
        for (int m = 1; m <= 8; m <<= 1) sq += __shfl_xor(sq, m, 64);
        float o = v * (sqrtf(sq) / (1.0f + sq));
        if (p1) {
            float v1 = p1[(size_t)b * 160 + tid];
            float sq1 = v1 * v1;
#pragma unroll
            for (int m = 1; m <= 8; m <<= 1) sq1 += __shfl_xor(sq1, m, 64);
            o += v1 * (sqrtf(sq1) / (1.0f + sq1));
        }
        o_s[tid] = o;
    }
    __syncthreads();

    float sp[NN][4];
#pragma unroll
    for (int n = 0; n < NN; ++n)
#pragma unroll
        for (int j = 0; j < 4; ++j) sp[n][j] = 0.f;

#pragma unroll
    for (int step = 0; step < 2; ++step) {
        float p[NN];
#pragma unroll
        for (int n = 0; n < NN; ++n) {
            uint2 r = step ? r1[n] : r0[n];
            float4 o4 = *(const float4*)&o_s[(n << 4) + (ld << 2)];  // broadcast
            p[n] = bflo(r.x) * o4.x + bfhi(r.x) * o4.y
                 + bflo(r.y) * o4.z + bfhi(r.y) * o4.w;
        }
        float a[NN];
#pragma unroll
        for (int n = 0; n < NN; ++n) {
            float t2 = p[n] + __shfl_xor(p[n], 1, 64);
            a[n] = t2 + __shfl_xor(t2, 2, 64);
        }
        float m = a[0];
#pragma unroll
        for (int n = 1; n < NN; ++n) m = fmaxf(m, a[n]);
        float c[NN], ssum = 0.f;
#pragma unroll
        for (int n = 0; n < NN; ++n) { c[n] = __expf(a[n] - m); ssum += c[n]; }
        float inv = 1.0f / ssum;
#pragma unroll
        for (int n = 0; n < NN; ++n) {
            uint2 r = step ? r1[n] : r0[n];
            float w = c[n] * inv;
            sp[n][0] += w * bflo(r.x); sp[n][1] += w * bfhi(r.x);
            sp[n][2] += w * bflo(r.y); sp[n][3] += w * bfhi(r.y);
        }
    }

    // block reduce -> 160 atomics
#pragma unroll
    for (int m = 4; m <= 32; m <<= 1)
#pragma unroll
        for (int n = 0; n < NN; ++n)
#pragma unroll
            for (int j = 0; j < 4; ++j)
                sp[n][j] += __shfl_xor(sp[n][j], m, 64);
    const int lane = tid & 63, wv = tid >> 6;
    if (lane < 4) {
#pragma unroll
        for (int n = 0; n < NN; ++n)
#pragma unroll
            for (int j = 0; j < 4; ++j)
                red[(wv * NN + n) * 16 + ld * 4 + j] = sp[n][j];
    }
    __syncthreads();
    if (tid < 160) {
        int n = tid >> 4, dd = tid & 15;
        float v = red[(0 * NN + n) * 16 + dd] + red[(1 * NN + n) * 16 + dd]
                + red[(2 * NN + n) * 16 + dd] + red[(3 * NN + n) * 16 + dd];
        atomicAdd(pout + (size_t)b * 160 + tid, v);
    }
}

// ---------------- output: squash(p2[b]) -------------------------------------
__global__ __launch_bounds__(192) void caps_out(const float* __restrict__ p2,
                                                float* __restrict__ out, int b0)
{
    const int b = b0 + blockIdx.x;
    const int t = threadIdx.x;
    if (t < 160) {
        float v = p2[(size_t)b * 160 + t];
        float sq = v * v;
#pragma unroll
        for (int m = 1; m <= 8; m <<= 1) sq += __shfl_xor(sq, m, 64);
        out[(size_t)b * 160 + t] = v * (sqrtf(sq) / (1.0f + sq));
    }
}

extern "C" void kernel_launch(void* const* d_in, const int* in_sizes, int n_in,
                              void* d_out, int out_size, void* d_ws, size_t ws_size,
                              hipStream_t stream)
{
    const float* xg = (const float*)d_in[0];  // [B,I,K]
    const float* wg = (const float*)d_in[1];  // [N,I,D,K]
    if (n_in >= 2 && in_sizes[0] == NN * II * DD * KK) {
        const float* t = xg; xg = wg; wg = t;
    }
    float* outp = (float*)d_out;

    const size_t perB  = (size_t)NN * II * DD * 2;       // 368,640 B bf16 u per b
    const size_t partsB = (size_t)3 * BN * 160 * 4;      // 491,520 B
    size_t avail = (ws_size > partsB) ? ws_size - partsB : 0;
    int C = 256;
    if (avail < (size_t)256 * perB) {
        C = (int)(avail / perB);
        C &= ~15;
        if (C < 16) C = 16;
    }
    ushort_t* uws = (ushort_t*)d_ws;
    float* part0 = (float*)((char*)d_ws + (size_t)C * perB);
    float* part1 = part0 + (size_t)BN * 160;
    float* part2 = part1 + (size_t)BN * 160;

    hipMemsetAsync(part0, 0, partsB, stream);

    for (int b0 = 0; b0 < BN; b0 += C) {
        int c = (BN - b0 < C) ? (BN - b0) : C;
        int c2 = c / 2;
        caps_uhat_s0<<<36 * c2, 256, 0, stream>>>(xg, wg, uws, part0, b0, c2);
        caps_sweep  <<<c * NCH, 256, 0, stream>>>(uws, part0, nullptr, part1, b0);
        caps_sweep  <<<c * NCH, 256, 0, stream>>>(uws, part0, part1,  part2, b0);
        caps_out    <<<c,       192, 0, stream>>>(part2, outp, b0);
    }
}

// Round 7
// 175.778 us; speedup vs baseline: 1.2631x; 1.2631x over previous
//
#include <hip/hip_runtime.h>
#include <stdint.h>

// CapsuleLayer dynamic routing, MI355X. fp32 in/out.
// B=256, N=10, I=1152, D=16, K(Din)=8, ROUTINGS=3.
// R7: no atomics anywhere (R6 lesson: device atomics to hot region = +47MB
// write-through + serialization). K1 = R5 + W[n+1] register prefetch.
// Sweeps = R5 body + preloaded u + NCH=9 grid. Deterministic partial buffers.

#define BN 256
#define NN 10
#define II 1152
#define DD 16
#define KK 8
#define NT 18          // K1 i-tiles of 64 (part0 partials)
#define NCH 9          // sweep chunks of 128 i
#define CHI 128

typedef unsigned short ushort_t;
typedef unsigned int uint_t;

__device__ __forceinline__ float bflo(uint_t u) {
    union { uint_t i; float f; } v; v.i = u << 16; return v.f;
}
__device__ __forceinline__ float bfhi(uint_t u) {
    union { uint_t i; float f; } v; v.i = u & 0xffff0000u; return v.f;
}
__device__ __forceinline__ uint_t f2bf(float f) {  // RTNE bf16
    union { float f; uint_t i; } v; v.f = f;
    uint_t x = v.i;
    return (x + 0x7fffu + ((x >> 16) & 1u)) >> 16;
}

// ---------------- K1 + sweep0 partials --------------------------------------
// block = (i-tile of 64, b-quad). 256 thr = 4 waves.
// lane = il*4+dq: thread owns (i = it*64 + wv*16 + il, d-quad dq), 4 b's.
// W[n+1] prefetched into registers while computing n.
// part0[b][it][n*16+d] = 0.1 * sum_{i in tile} u  (fp32, pre-pack values).
__global__ __launch_bounds__(256) void caps_uhat_s0(const float* __restrict__ xg,
                                                    const float* __restrict__ wg,
                                                    ushort_t* __restrict__ u,
                                                    float* __restrict__ part0,
                                                    int b0, int c4)
{
    __shared__ float red[16][NN][16];   // [wv*4+dq][n][bb*4+dj], 10 KB
    const int tid = threadIdx.x;
    const int lane = tid & 63, wv = tid >> 6;
    const int dq = lane & 3, il = lane >> 2;
    const int it = blockIdx.x / c4;
    const int bl = (blockIdx.x % c4) * 4;      // chunk-local b base (4 b's)
    const int i = it * 64 + wv * 16 + il;

    float xv[4][8];
#pragma unroll
    for (int bb = 0; bb < 4; ++bb) {
        const float4* xp = (const float4*)(xg + ((size_t)(b0 + bl + bb) * II + i) * KK);
        float4 x0 = xp[0], x1 = xp[1];
        xv[bb][0] = x0.x; xv[bb][1] = x0.y; xv[bb][2] = x0.z; xv[bb][3] = x0.w;
        xv[bb][4] = x1.x; xv[bb][5] = x1.y; xv[bb][6] = x1.z; xv[bb][7] = x1.w;
    }

    // W pipeline: thread reads W[n][i][dq*4..dq*4+3][*] = 128 contiguous B.
    float4 wcur[8];
    {
        const float4* wp = (const float4*)(wg + (size_t)(0 * II + i) * (DD * KK)) + dq * 8;
#pragma unroll
        for (int j = 0; j < 8; ++j) wcur[j] = wp[j];
    }

#pragma unroll
    for (int n = 0; n < NN; ++n) {
        float4 wnxt[8];
        if (n < NN - 1) {
            const float4* wp = (const float4*)(wg + (size_t)((n + 1) * II + i) * (DD * KK)) + dq * 8;
#pragma unroll
            for (int j = 0; j < 8; ++j) wnxt[j] = wp[j];
        }

        float s[4][4];   // [bb][dj]
#pragma unroll
        for (int dj = 0; dj < 4; ++dj) {
            float4 wa = wcur[2 * dj], wb = wcur[2 * dj + 1];
#pragma unroll
            for (int bb = 0; bb < 4; ++bb) {
                s[bb][dj] = wa.x * xv[bb][0] + wa.y * xv[bb][1]
                          + wa.z * xv[bb][2] + wa.w * xv[bb][3]
                          + wb.x * xv[bb][4] + wb.y * xv[bb][5]
                          + wb.z * xv[bb][6] + wb.w * xv[bb][7];
            }
        }
        // store u (bf16): wave-contiguous 512 B per (b,n)
#pragma unroll
        for (int bb = 0; bb < 4; ++bb) {
            uint2 q;
            q.x = f2bf(s[bb][0]) | (f2bf(s[bb][1]) << 16);
            q.y = f2bf(s[bb][2]) | (f2bf(s[bb][3]) << 16);
            *(uint2*)(u + (((size_t)(bl + bb) * NN + n) * II + i) * DD + dq * 4) = q;
        }
        // reduce over the 16 il lanes (masks 4,8,16,32)
#pragma unroll
        for (int m = 4; m <= 32; m <<= 1)
#pragma unroll
            for (int bb = 0; bb < 4; ++bb)
#pragma unroll
                for (int dj = 0; dj < 4; ++dj)
                    s[bb][dj] += __shfl_xor(s[bb][dj], m, 64);
        if (il == 0) {
#pragma unroll
            for (int bb = 0; bb < 4; ++bb)
#pragma unroll
                for (int dj = 0; dj < 4; ++dj)
                    red[wv * 4 + dq][n][bb * 4 + dj] = s[bb][dj];
        }
#pragma unroll
        for (int j = 0; j < 8; ++j) wcur[j] = wnxt[j];
    }
    __syncthreads();
#pragma unroll
    for (int idx = tid; idx < 640; idx += 256) {
        int bb = idx / 160, r = idx - bb * 160;
        int n = r >> 4, d = r & 15, q2 = d >> 2, dj = d & 3;
        float v = red[0 + q2][n][bb * 4 + dj] + red[4 + q2][n][bb * 4 + dj]
                + red[8 + q2][n][bb * 4 + dj] + red[12 + q2][n][bb * 4 + dj];
        part0[((size_t)(b0 + bl + bb) * NT + it) * 160 + r] = 0.1f * v;
    }
}

// ---- block reduction of sp[NN][4] over 64 groups -> 160 floats -------------
__device__ __forceinline__ void block_reduce_part(float sp[NN][4], int tid,
                                                  float* red,
                                                  float* __restrict__ partp)
{
#pragma unroll
    for (int m = 4; m <= 32; m <<= 1)
#pragma unroll
        for (int n = 0; n < NN; ++n)
#pragma unroll
            for (int j = 0; j < 4; ++j)
                sp[n][j] += __shfl_xor(sp[n][j], m, 64);

    const int lane = tid & 63, wv = tid >> 6, ld = tid & 3;
    if (lane < 4) {
#pragma unroll
        for (int n = 0; n < NN; ++n)
#pragma unroll
            for (int j = 0; j < 4; ++j)
                red[(wv * NN + n) * 16 + ld * 4 + j] = sp[n][j];
    }
    __syncthreads();
    if (tid < 160) {
        int n = tid >> 4, dd = tid & 15;
        float v = 0.f;
#pragma unroll
        for (int w = 0; w < 4; ++w) v += red[(w * NN + n) * 16 + dd];
        partp[tid] = v;
    }
}

// ---------------- sweep r=1,2 ----------------------------------------------
// o = squash(sum_{18} p0[b]); if p1: o += squash(sum_{9} p1[b]).
// c = softmax_n(<o,u>), partial s = sum c*u over 128 i -> pout[b][ch][160].
__global__ __launch_bounds__(256) void caps_sweep(const ushort_t* __restrict__ u,
                                                  const float* __restrict__ p0,
                                                  const float* __restrict__ p1,
                                                  float* __restrict__ pout, int b0)
{
    __shared__ float red[4 * 160];
    __shared__ float o_s[160];
    const int tid = threadIdx.x, g = tid >> 2, ld = tid & 3;
    const int cb = blockIdx.x / NCH, ch = blockIdx.x % NCH;
    const int b = b0 + cb;
    const ushort_t* ub = u + (size_t)cb * (NN * II * DD);

    // issue ALL u loads first: they drain while the prologue runs.
    const int i0 = ch * CHI + g;
    uint2 r0[NN], r1[NN];
#pragma unroll
    for (int n = 0; n < NN; ++n) {
        r0[n] = *(const uint2*)(ub + ((size_t)(n * II + i0)) * DD + ld * 4);
        r1[n] = *(const uint2*)(ub + ((size_t)(n * II + i0 + 64)) * DD + ld * 4);
    }

    if (tid < 160) {
        float v = 0.f;
#pragma unroll
        for (int t = 0; t < NT; ++t)
            v += p0[((size_t)b * NT + t) * 160 + tid];
        float sq = v * v;
#pragma unroll
        for (int m = 1; m <= 8; m <<= 1) sq += __shfl_xor(sq, m, 64);
        float o = v * (sqrtf(sq) / (1.0f + sq));
        if (p1) {
            float v1 = 0.f;
#pragma unroll
            for (int c2 = 0; c2 < NCH; ++c2)
                v1 += p1[((size_t)b * NCH + c2) * 160 + tid];
            float sq1 = v1 * v1;
#pragma unroll
            for (int m = 1; m <= 8; m <<= 1) sq1 += __shfl_xor(sq1, m, 64);
            o += v1 * (sqrtf(sq1) / (1.0f + sq1));
        }
        o_s[tid] = o;
    }
    __syncthreads();

    float sp[NN][4];
#pragma unroll
    for (int n = 0; n < NN; ++n)
#pragma unroll
        for (int j = 0; j < 4; ++j) sp[n][j] = 0.f;

#pragma unroll
    for (int step = 0; step < 2; ++step) {
        float p[NN];
#pragma unroll
        for (int n = 0; n < NN; ++n) {
            uint2 r = step ? r1[n] : r0[n];
            float4 o4 = *(const float4*)&o_s[(n << 4) + (ld << 2)];  // broadcast
            p[n] = bflo(r.x) * o4.x + bfhi(r.x) * o4.y
                 + bflo(r.y) * o4.z + bfhi(r.y) * o4.w;
        }
        float a[NN];
#pragma unroll
        for (int n = 0; n < NN; ++n) {
            float t2 = p[n] + __shfl_xor(p[n], 1, 64);
            a[n] = t2 + __shfl_xor(t2, 2, 64);
        }
        float m = a[0];
#pragma unroll
        for (int n = 1; n < NN; ++n) m = fmaxf(m, a[n]);
        float c[NN], ssum = 0.f;
#pragma unroll
        for (int n = 0; n < NN; ++n) { c[n] = __expf(a[n] - m); ssum += c[n]; }
        float inv = 1.0f / ssum;
#pragma unroll
        for (int n = 0; n < NN; ++n) {
            uint2 r = step ? r1[n] : r0[n];
            float w = c[n] * inv;
            sp[n][0] += w * bflo(r.x); sp[n][1] += w * bfhi(r.x);
            sp[n][2] += w * bflo(r.y); sp[n][3] += w * bfhi(r.y);
        }
    }
    block_reduce_part(sp, tid, red, pout + ((size_t)b * NCH + ch) * 160);
}

// ---------------- output: squash(sum_ch part2) ------------------------------
__global__ __launch_bounds__(192) void caps_out(const float* __restrict__ p2,
                                                float* __restrict__ out, int b0)
{
    const int b = b0 + blockIdx.x;
    const int t = threadIdx.x;
    if (t < 160) {
        float v = 0.f;
#pragma unroll
        for (int ch = 0; ch < NCH; ++ch)
            v += p2[((size_t)b * NCH + ch) * 160 + t];
        float sq = v * v;
#pragma unroll
        for (int m = 1; m <= 8; m <<= 1) sq += __shfl_xor(sq, m, 64);
        out[(size_t)b * 160 + t] = v * (sqrtf(sq) / (1.0f + sq));
    }
}

extern "C" void kernel_launch(void* const* d_in, const int* in_sizes, int n_in,
                              void* d_out, int out_size, void* d_ws, size_t ws_size,
                              hipStream_t stream)
{
    const float* xg = (const float*)d_in[0];  // [B,I,K]
    const float* wg = (const float*)d_in[1];  // [N,I,D,K]
    if (n_in >= 2 && in_sizes[0] == NN * II * DD * KK) {
        const float* t = xg; xg = wg; wg = t;
    }
    float* outp = (float*)d_out;

    const size_t perB  = (size_t)NN * II * DD * 2;       // 368,640 B bf16 u per b
    const size_t p0B   = (size_t)BN * NT * 160 * 4;      // 2,949,120
    const size_t p12B  = (size_t)BN * NCH * 160 * 4;     // 1,474,560 each
    size_t extra = p0B + 2 * p12B;
    size_t avail = (ws_size > extra) ? ws_size - extra : 0;
    int C = 256;
    if (avail < (size_t)256 * perB) {
        C = (int)(avail / perB);
        C &= ~15;
        if (C < 16) C = 16;
    }
    ushort_t* uws = (ushort_t*)d_ws;
    float* part0 = (float*)((char*)d_ws + (size_t)C * perB);
    float* part1 = part0 + (size_t)BN * NT * 160;
    float* part2 = part1 + (size_t)BN * NCH * 160;

    for (int b0 = 0; b0 < BN; b0 += C) {
        int c = (BN - b0 < C) ? (BN - b0) : C;
        int c4 = c / 4;
        caps_uhat_s0<<<NT * c4, 256, 0, stream>>>(xg, wg, uws, part0, b0, c4);
        caps_sweep  <<<c * NCH, 256, 0, stream>>>(uws, part0, nullptr, part1, b0);
        caps_sweep  <<<c * NCH, 256, 0, stream>>>(uws, part0, part1,  part2, b0);
        caps_out    <<<c,       192, 0, stream>>>(part2, outp, b0);
    }
}